// Round 14
// baseline (380.966 us; speedup 1.0000x reference)
//
#include <hip/hip_runtime.h>
#include <hip/hip_bf16.h>
#include <stdint.h>
#include <stddef.h>

#define DF 384
#define DP 256
#define NPROT 8
#define NPB 4096
#define KSTEPS 12

typedef __attribute__((ext_vector_type(8))) short bf16x8;
typedef __attribute__((ext_vector_type(4))) short bf16x4;
typedef __attribute__((ext_vector_type(4))) float f32x4;

typedef const __attribute__((address_space(1))) unsigned char as1_u8;
typedef __attribute__((address_space(3))) unsigned char as3_u8;

static __device__ __forceinline__ short f2bf(float f) {
  __hip_bfloat16 h(f);
  return *reinterpret_cast<short*>(&h);
}
// fast GELU: NaN-safe, |err| ~1e-3 << 0.112 budget (validated R9-R12: absmax 0.03125)
static __device__ __forceinline__ float gelu_f(float x) {
  float x3 = x * x * x;
  float t = __expf(1.5957691216057308f * fmaf(0.044715f, x3, x));
  return x - x / (t + 1.0f);
}

static __device__ __forceinline__ f32x4 mfma16x16x16_bf16(bf16x4 a, bf16x4 b, f32x4 c) {
#if __has_builtin(__builtin_amdgcn_mfma_f32_16x16x16bf16_1k)
  return __builtin_amdgcn_mfma_f32_16x16x16bf16_1k(a, b, c, 0, 0, 0);
#else
  asm volatile("v_mfma_f32_16x16x16_bf16 %0, %1, %2, %0" : "+v"(c) : "v"(a), "v"(b));
  return c;
#endif
}

// ---------- setup: wT (bf16 W_projT) + protoN + proto B-fragments ----------
__global__ __launch_bounds__(256) void k_setup(const float* __restrict__ W,
                                               unsigned short* __restrict__ wT,
                                               const float* __restrict__ P,
                                               float* __restrict__ PN,
                                               unsigned short* __restrict__ pb) {
  if (blockIdx.x < 384) {
    int e = blockIdx.x * 256 + threadIdx.x;
    int c = e / DF;
    int k = e - c * DF;
    wT[e] = (unsigned short)f2bf(W[k * DP + c]);
  } else {
    __shared__ float s_red[4];
    __shared__ float s_pn[NPROT][DP];
    const int tid = threadIdx.x;
    const int lane = tid & 63, wave = tid >> 6;
    for (int r = 0; r < NPROT; r++) {
      float x = P[r * DP + tid];
      float q = x * x;
      #pragma unroll
      for (int d = 1; d < 64; d <<= 1) q += __shfl_xor(q, d);
      if (lane == 0) s_red[wave] = q;
      __syncthreads();
      float ss = s_red[0] + s_red[1] + s_red[2] + s_red[3];
      float v = x / fmaxf(sqrtf(ss), 1e-12f);
      PN[r * DP + tid] = v;
      s_pn[r][tid] = v;
      __syncthreads();
    }
    for (int i = tid; i < 512; i += 256) {
      int step = i >> 6, l = i & 63;
      int k = l & 15, g = l >> 4;
      bf16x8 v;
      #pragma unroll
      for (int j = 0; j < 8; j++) {
        int d = step * 32 + g * 8 + j;
        v[j] = (k < NPROT) ? f2bf(s_pn[k][d]) : (short)0;
      }
      *(bf16x8*)(pb + (size_t)i * 8) = v;
    }
  }
}

// ---------- fused, 8-wave col-split: 64x256 tile, wave = 16 rows x 128 cols ----
// acc/thread 64 -> 32 f32. launch_bounds(512,4): 128-reg cap -> 2 blocks/CU =
// 16 waves/CU (vs 12). R13 bug fixed here: the per-wave transpose slice is
// [16][68] (64 cols + 4 pad) processed in TWO 64-col passes -- all indices now
// bounded by the 68-float row stride (R13 wrote/read 128-col offsets into a
// 68-stride buffer -> corruption).
__global__ __launch_bounds__(512, 4) void k_fused(
    const float* __restrict__ patch,
    const float* __restrict__ bias,
    const float* __restrict__ g1,
    const float* __restrict__ beta1,
    const unsigned short* __restrict__ wT,
    const unsigned short* __restrict__ pb,
    float* __restrict__ out_feat,
    float* __restrict__ out_assign,
    float* __restrict__ part_partial,
    float* __restrict__ mp_partial,
    float* __restrict__ acc_part,
    float* __restrict__ acc_mass,
    float* __restrict__ acc_pos,
    int use_part) {
  // Bbuf timeline: K-loop 2x16KB double buffer -> per-wave transpose slices
  // [8][16][68] floats (34816B) -> part C [4][8][256] floats (32768B).
  __shared__ __align__(16) unsigned char Bbuf[35840];
  __shared__ __align__(16) unsigned short s_pb[512 * 8];   // 8 KB proto frags
  __shared__ float s_bias[DP], s_g1[DP], s_b1[DP];
  __shared__ float2 s_ln[2][64];                           // (sum, sumsq) per col-half
  __shared__ float s_ss[2][64];                            // post-GELU sumsq partials
  __shared__ __align__(16) float s_cd[8 * 64 * 4];         // cdot partials per wave
  __shared__ float s_asg[64 * 8];                          // softmax result share
  __shared__ float s_mp[4][3][NPROT];

  const int tid  = threadIdx.x;
  const int lane = tid & 63;
  const int wave = tid >> 6;      // 0..7
  const int rg   = wave >> 1;     // row group (16 rows each)
  const int ch   = wave & 1;      // col half (128 cols each)
  const int mrow = lane & 15;
  const int kgrp = lane >> 4;

  const long long row0 = (long long)blockIdx.x * 64;
  const int b  = (int)(row0 >> 12);
  const int n0 = (int)(row0 & 4095);

  if (tid < DP) {
    s_bias[tid] = bias[tid];
    s_g1[tid]   = g1[tid];
    s_b1[tid]   = beta1[tid];
  }
  *(bf16x8*)(s_pb + (size_t)tid * 8) = *(const bf16x8*)(pb + (size_t)tid * 8);

  // STAGE: 512 threads x 2 chunks x 16B = 16KB slab. col = i*128 + (tid>>2);
  // sub = (tid&3)^((col>>1)&3) = (tid&3)^((tid>>3)&3), uniform in i.
  const unsigned short* bsrc =
      wT + (tid >> 2) * DF + ((tid & 3) ^ ((tid >> 3) & 3)) * 8;
  const int lofs0 = __builtin_amdgcn_readfirstlane(wave * 1024);

  #define STAGE(kt_, q_)                                                        \
    {                                                                           \
      _Pragma("unroll")                                                         \
      for (int i = 0; i < 2; i++) {                                             \
        __builtin_amdgcn_global_load_lds(                                       \
            (as1_u8*)(const void*)(bsrc + i * 49152 + (kt_) * 32),              \
            (as3_u8*)(void*)(Bbuf + (q_) * 16384 + i * 8192 + lofs0), 16, 0, 0);\
      }                                                                         \
    }

  // ---- prologue ----
  STAGE(0, 0);
  const float* arow = patch + (size_t)(row0 + rg * 16 + mrow) * DF + kgrp * 8;
  bf16x8 afrag[KSTEPS];
  #pragma unroll
  for (int kt = 0; kt < KSTEPS; kt++) {
    float4 x0 = *(const float4*)(arow + kt * 32);
    float4 x1 = *(const float4*)(arow + kt * 32 + 4);
    bf16x8 a;
    a[0] = f2bf(x0.x); a[1] = f2bf(x0.y); a[2] = f2bf(x0.z); a[3] = f2bf(x0.w);
    a[4] = f2bf(x1.x); a[5] = f2bf(x1.y); a[6] = f2bf(x1.z); a[7] = f2bf(x1.w);
    afrag[kt] = a;
  }
  f32x4 acc[8];
  #pragma unroll
  for (int f = 0; f < 8; f++) acc[f] = (f32x4){0.f, 0.f, 0.f, 0.f};
  __syncthreads();   // buf0 ready, s_pb/s_bias visible

  // read addr: col = ch*128 + f*16 + mrow; slot = kgrp ^ ((mrow>>1)&3)
  // (f*8 == 0 mod 4 -> slot f-independent); byte = col*64 + slot*16.
  const int lane_swz = ch * 8192 + mrow * 64 + (kgrp ^ ((mrow >> 1) & 3)) * 16;

  #pragma unroll
  for (int kt = 0; kt < KSTEPS; kt++) {
    if (kt + 1 < KSTEPS) STAGE(kt + 1, (kt + 1) & 1);   // in flight across MFMAs
    const unsigned char* bbase = Bbuf + (kt & 1) * 16384 + lane_swz;
    bf16x8 a = afrag[kt];
    #pragma unroll
    for (int f = 0; f < 8; f++) {
      bf16x8 bf = *(const bf16x8*)(bbase + f * 1024);
      acc[f] = __builtin_amdgcn_mfma_f32_16x16x32_bf16(a, bf, acc[f], 0, 0, 0);
    }
    asm volatile("s_waitcnt vmcnt(0) lgkmcnt(0)" ::: "memory");
    __builtin_amdgcn_s_barrier();
    __builtin_amdgcn_sched_barrier(0);
  }
  #undef STAGE

  // ---- bias ----
  #pragma unroll
  for (int f = 0; f < 8; f++) {
    const float bb = s_bias[ch * 128 + f * 16 + mrow];
    #pragma unroll
    for (int r = 0; r < 4; r++) acc[f][r] += bb;
  }
  // ---- LN partials per col-half -> exchange -> GELU ----
  #pragma unroll
  for (int r = 0; r < 4; r++) {
    float s = 0.f, q = 0.f;
    #pragma unroll
    for (int f = 0; f < 8; f++) { float x = acc[f][r]; s += x; q += x * x; }
    #pragma unroll
    for (int d = 1; d < 16; d <<= 1) { s += __shfl_xor(s, d); q += __shfl_xor(q, d); }
    if (mrow == 0) s_ln[ch][rg * 16 + kgrp * 4 + r] = make_float2(s, q);
  }
  __syncthreads();   // barrier L
  #pragma unroll
  for (int r = 0; r < 4; r++) {
    const int grow = rg * 16 + kgrp * 4 + r;
    float2 h0 = s_ln[0][grow], h1 = s_ln[1][grow];
    const float mean = (h0.x + h1.x) * (1.f / 256.f);
    const float var  = (h0.y + h1.y) * (1.f / 256.f) - mean * mean;
    const float rstd = rsqrtf(var + 1e-5f);
    #pragma unroll
    for (int f = 0; f < 8; f++) {
      const int col = ch * 128 + f * 16 + mrow;
      acc[f][r] = gelu_f((acc[f][r] - mean) * rstd * s_g1[col] + s_b1[col]);
    }
  }
  // ---- ss partials (read after barrier C) ----
  #pragma unroll
  for (int r = 0; r < 4; r++) {
    float q2 = 0.f;
    #pragma unroll
    for (int f = 0; f < 8; f++) q2 += acc[f][r] * acc[f][r];
    #pragma unroll
    for (int d = 1; d < 16; d <<= 1) q2 += __shfl_xor(q2, d);
    if (mrow == 0) s_ss[ch][rg * 16 + kgrp * 4 + r] = q2;
  }

  // ---- transpose in TWO 64-col passes + feat store + partial cdot ----
  // Wave-private [16][68] slice (64 data cols + 4 pad); per pass p the slice
  // holds cols [ch*128 + p*64, +64). All indices < 68-float row stride.
  f32x4 cdot = (f32x4){0.f, 0.f, 0.f, 0.f};
  {
    float* s_trW = (float*)Bbuf + wave * 1088;   // [16][68]
    float* fb = out_feat + (size_t)(row0 + rg * 16) * DP + ch * 128;
    const int aoff = mrow * 68 + kgrp * 8;
    #pragma unroll
    for (int p = 0; p < 2; p++) {
      #pragma unroll
      for (int fl = 0; fl < 4; fl++) {
        const int f = p * 4 + fl;
        #pragma unroll
        for (int r = 0; r < 4; r++)
          s_trW[(kgrp * 4 + r) * 68 + fl * 16 + mrow] = acc[f][r];
      }
      // feat store: 16 rows x 64 cols, coalesced f32x4
      #pragma unroll
      for (int j = 0; j < 4; j++) {
        const int idx = j * 64 + lane;       // 0..255
        const int row = idx >> 4;            // 0..15
        const int c4  = (idx & 15) * 4;      // 0..60
        f32x4 v = *(const f32x4*)&s_trW[row * 68 + c4];
        *(f32x4*)&fb[(size_t)row * DP + p * 64 + c4] = v;
      }
      // sim MFMA over this 64-d chunk: 2 steps of K=32
      #pragma unroll
      for (int s = 0; s < 2; s++) {
        float4 y0 = *(const float4*)&s_trW[aoff + s * 32];
        float4 y1 = *(const float4*)&s_trW[aoff + s * 32 + 4];
        bf16x8 a;
        a[0] = f2bf(y0.x); a[1] = f2bf(y0.y); a[2] = f2bf(y0.z); a[3] = f2bf(y0.w);
        a[4] = f2bf(y1.x); a[5] = f2bf(y1.y); a[6] = f2bf(y1.z); a[7] = f2bf(y1.w);
        const int step = ch * 4 + p * 2 + s;
        bf16x8 pf = *(const bf16x8*)(s_pb + (size_t)(step * 64 + lane) * 8);
        cdot = __builtin_amdgcn_mfma_f32_16x16x32_bf16(a, pf, cdot, 0, 0, 0);
      }
    }
  }
  *(f32x4*)&s_cd[(size_t)(wave * 64 + lane) * 4] = cdot;
  __syncthreads();   // barrier C: s_cd + s_ss visible; all s_trW reads done

  // ---- softmax on col-half-0 waves; share asg ----
  if (ch == 0) {
    f32x4 oth = *(const f32x4*)&s_cd[(size_t)((wave + 1) * 64 + lane) * 4];
    float asg[4];
    #pragma unroll
    for (int r = 0; r < 4; r++) {
      const int grow = rg * 16 + kgrp * 4 + r;
      const float ssn = s_ss[0][grow] + s_ss[1][grow];
      const float nrm = fmaxf(sqrtf(ssn), 1e-12f);
      float lg = (mrow < NPROT) ? ((cdot[r] + oth[r]) / nrm) * (1.f / 0.07f) : -1e30f;
      float mx = lg;
      #pragma unroll
      for (int d = 1; d < 16; d <<= 1) mx = fmaxf(mx, __shfl_xor(mx, d));
      float e = __expf(lg - mx);
      float se = e;
      #pragma unroll
      for (int d = 1; d < 16; d <<= 1) se += __shfl_xor(se, d);
      asg[r] = e / se;
    }
    float pm = 0.f, px = 0.f, py = 0.f;
    #pragma unroll
    for (int r = 0; r < 4; r++) {
      const int n = n0 + rg * 16 + kgrp * 4 + r;
      if (mrow < NPROT) {
        out_assign[((size_t)b * NPB + n) * NPROT + mrow] = asg[r];
        s_asg[(rg * 16 + kgrp * 4 + r) * 8 + mrow] = asg[r];
      }
      const float cx = (float)(n & 63) * (1.f / 63.f);
      const float cy = (float)(n >> 6) * (1.f / 63.f);
      pm += asg[r]; px += asg[r] * cx; py += asg[r] * cy;
    }
    pm += __shfl_xor(pm, 16); pm += __shfl_xor(pm, 32);
    px += __shfl_xor(px, 16); px += __shfl_xor(px, 32);
    py += __shfl_xor(py, 16); py += __shfl_xor(py, 32);
    if (lane < NPROT) {
      s_mp[rg][0][lane] = pm;
      s_mp[rg][1][lane] = px;
      s_mp[rg][2][lane] = py;
    }
  }
  __syncthreads();   // barrier A2: s_asg visible; Bbuf free for s_partw

  // ---- part via MFMA 16x16x16: A = asg (from s_asg), B = acc directly ----
  {
    float* s_partw = (float*)Bbuf;   // [4][8][256]
    bf16x4 a4;
    #pragma unroll
    for (int j = 0; j < 4; j++) {
      float v = (mrow < NPROT) ? s_asg[(rg * 16 + kgrp * 4 + j) * 8 + mrow] : 0.f;
      a4[j] = f2bf(v);
    }
    #pragma unroll
    for (int f = 0; f < 8; f++) {
      bf16x4 b4;
      #pragma unroll
      for (int j = 0; j < 4; j++) b4[j] = f2bf(acc[f][j]);
      f32x4 c = mfma16x16x16_bf16(a4, b4, (f32x4){0.f, 0.f, 0.f, 0.f});
      if (kgrp < 2) {
        #pragma unroll
        for (int r = 0; r < 4; r++)
          s_partw[(rg * 8 + kgrp * 4 + r) * 256 + ch * 128 + f * 16 + mrow] = c[r];
      }
    }
  }
  __syncthreads();   // barrier F

  // ---- combine across row groups + flush ----
  {
    const float* s_partw = (const float*)Bbuf;
    if (use_part) {
      float* pp = part_partial + (size_t)blockIdx.x * 2048;
      #pragma unroll
      for (int i = 0; i < 4; i++) {
        const int idx = i * 512 + tid;           // idx = kp*256 + col
        const int kp = idx >> 8, col = idx & 255;
        float pr = s_partw[(0 * 8 + kp) * 256 + col] + s_partw[(1 * 8 + kp) * 256 + col] +
                   s_partw[(2 * 8 + kp) * 256 + col] + s_partw[(3 * 8 + kp) * 256 + col];
        pp[idx] = pr;
      }
      if (tid < 24) {
        const int v = tid >> 3, k = tid & 7;
        float s = s_mp[0][v][k] + s_mp[1][v][k] + s_mp[2][v][k] + s_mp[3][v][k];
        mp_partial[(size_t)blockIdx.x * 32 + v * 8 + k] = s;
      }
    } else {
      float* gp = acc_part + (size_t)b * (NPROT * DP);
      #pragma unroll
      for (int i = 0; i < 4; i++) {
        const int idx = i * 512 + tid;
        const int kp = idx >> 8, col = idx & 255;
        float pr = s_partw[(0 * 8 + kp) * 256 + col] + s_partw[(1 * 8 + kp) * 256 + col] +
                   s_partw[(2 * 8 + kp) * 256 + col] + s_partw[(3 * 8 + kp) * 256 + col];
        atomicAdd(&gp[idx], pr);
      }
      if (tid < 24) {
        const int v = tid >> 3, k = tid & 7;
        float s = s_mp[0][v][k] + s_mp[1][v][k] + s_mp[2][v][k] + s_mp[3][v][k];
        if (v == 0) atomicAdd(&acc_mass[b * NPROT + k], s);
        else        atomicAdd(&acc_pos[(b * NPROT + k) * 2 + (v - 1)], s);
      }
    }
  }
}

// ---------- parallel reduction of part partials ----------
__global__ __launch_bounds__(256) void k_reduce(const float* __restrict__ pp,
                                                float* __restrict__ acc_part) {
  const int b = blockIdx.x >> 3;
  const int j = blockIdx.x & 7;
  const int col = j * 256 + threadIdx.x;
  const float* base = pp + (size_t)b * 64 * 2048 + col;
  float a0 = 0.f, a1 = 0.f, a2 = 0.f, a3 = 0.f;
  #pragma unroll
  for (int p = 0; p < 64; p += 4) {
    a0 += base[(size_t)p * 2048];
    a1 += base[(size_t)(p + 1) * 2048];
    a2 += base[(size_t)(p + 2) * 2048];
    a3 += base[(size_t)(p + 3) * 2048];
  }
  acc_part[(size_t)b * 2048 + col] = (a0 + a1) + (a2 + a3);
}

// ---------- per-batch finalize ----------
__global__ __launch_bounds__(256) void k_final(
    const float* __restrict__ mp_partial,
    const float* __restrict__ acc_part, const float* __restrict__ acc_mass,
    const float* __restrict__ acc_pos,
    const float* __restrict__ g2, const float* __restrict__ beta2,
    const float* __restrict__ W_r1, const float* __restrict__ b_r1,
    const float* __restrict__ W_r2, const float* __restrict__ b_r2,
    const float* __restrict__ W_s1, const float* __restrict__ b_s1,
    const float* __restrict__ W_s2, const float* __restrict__ b_s2,
    float* __restrict__ out_pf, float* __restrict__ out_pos, float* __restrict__ out_sal,
    int use_part) {
  __shared__ float s_pf[8 * DP];
  __shared__ float s_h[8 * DP];
  __shared__ float s_t[8 * 512];
  __shared__ float s_pff[8 * DP];
  __shared__ float s_s1v[8 * 64];
  __shared__ float s_m[8];
  __shared__ float s_red[8];
  const int b = blockIdx.x;
  const int tid = threadIdx.x;
  const int lane = tid & 63, wave = tid >> 6;

  if (use_part) {
    if (tid < 8) {
      float m = 0.f, x = 0.f, y = 0.f;
      for (int j = 0; j < 64; j++) {
        const float* q = mp_partial + ((size_t)b * 64 + j) * 32;
        m += q[tid]; x += q[8 + tid]; y += q[16 + tid];
      }
      m = fmaxf(m, 1e-6f);
      s_m[tid] = m;
      out_pos[b * 16 + tid * 2 + 0] = x / m;
      out_pos[b * 16 + tid * 2 + 1] = y / m;
    }
  } else {
    if (tid < 8) s_m[tid] = fmaxf(acc_mass[b * 8 + tid], 1e-6f);
    if (tid >= 64 && tid < 80) {
      int t = tid - 64;
      out_pos[b * 16 + t] = acc_pos[b * 16 + t] / fmaxf(acc_mass[b * 8 + (t >> 1)], 1e-6f);
    }
  }
  __syncthreads();
  #pragma unroll
  for (int i = 0; i < 8; i++) {
    int idx = i * 256 + tid;
    s_pf[idx] = acc_part[(size_t)b * 2048 + idx] / s_m[i];
  }
  __syncthreads();

  for (int r = 0; r < 8; r++) {
    float x = s_pf[r * DP + tid];
    float s = x, q = x * x;
    #pragma unroll
    for (int d = 1; d < 64; d <<= 1) { s += __shfl_xor(s, d); q += __shfl_xor(q, d); }
    if (lane == 0) { s_red[wave] = s; s_red[4 + wave] = q; }
    __syncthreads();
    float ts = s_red[0] + s_red[1] + s_red[2] + s_red[3];
    float tq = s_red[4] + s_red[5] + s_red[6] + s_red[7];
    float mean = ts * (1.f / 256.f);
    float var  = tq * (1.f / 256.f) - mean * mean;
    s_h[r * DP + tid] = (x - mean) * rsqrtf(var + 1e-5f) * g2[tid] + beta2[tid];
    __syncthreads();
  }

  #pragma unroll
  for (int i = 0; i < 2; i++) {
    const int o = i * 256 + tid;
    float a[8];
    #pragma unroll
    for (int r = 0; r < 8; r++) a[r] = 0.f;
    #pragma unroll 8
    for (int c = 0; c < DP; c++) {
      const float w = W_r1[c * 512 + o];
      #pragma unroll
      for (int r = 0; r < 8; r++) a[r] += s_h[r * DP + c] * w;
    }
    const float bb = b_r1[o];
    #pragma unroll
    for (int r = 0; r < 8; r++) s_t[r * 512 + o] = gelu_f(a[r] + bb);
  }
  __syncthreads();

  {
    const int o = tid;
    float a[8];
    #pragma unroll
    for (int r = 0; r < 8; r++) a[r] = 0.f;
    #pragma unroll 8
    for (int c = 0; c < 512; c++) {
      const float w = W_r2[c * DP + o];
      #pragma unroll
      for (int r = 0; r < 8; r++) a[r] += s_t[r * 512 + c] * w;
    }
    const float bb = b_r2[o];
    #pragma unroll
    for (int r = 0; r < 8; r++) {
      float v = s_pf[r * DP + o] + a[r] + bb;
      s_pff[r * DP + o] = v;
      out_pf[(size_t)b * 2048 + r * DP + o] = v;
    }
  }
  __syncthreads();

  if (tid < 64) {
    const int o = tid;
    float a[8];
    #pragma unroll
    for (int r = 0; r < 8; r++) a[r] = 0.f;
    #pragma unroll 8
    for (int c = 0; c < DP; c++) {
      const float w = W_s1[c * 64 + o];
      #pragma unroll
      for (int r = 0; r < 8; r++) a[r] += s_pff[r * DP + c] * w;
    }
    const float bb = b_s1[o];
    #pragma unroll
    for (int r = 0; r < 8; r++) s_s1v[r * 64 + o] = gelu_f(a[r] + bb);
  }
  __syncthreads();

  if (tid < 8) {
    float a = 0.f;
    for (int c = 0; c < 64; c++) a += s_s1v[tid * 64 + c] * W_s2[c];
    a += b_s2[0];
    out_sal[b * 8 + tid] = 1.f / (1.f + __expf(-a));
  }
}

extern "C" void kernel_launch(void* const* d_in, const int* in_sizes, int n_in,
                              void* d_out, int out_size, void* d_ws, size_t ws_size,
                              hipStream_t stream) {
  (void)in_sizes; (void)n_in; (void)out_size;
  const float* patch  = (const float*)d_in[0];
  const float* W_proj = (const float*)d_in[3];
  const float* b_proj = (const float*)d_in[4];
  const float* g1     = (const float*)d_in[5];
  const float* beta1  = (const float*)d_in[6];
  const float* proto  = (const float*)d_in[7];
  const float* g2     = (const float*)d_in[8];
  const float* beta2  = (const float*)d_in[9];
  const float* W_r1   = (const float*)d_in[10];
  const float* b_r1   = (const float*)d_in[11];
  const float* W_r2   = (const float*)d_in[12];
  const float* b_r2   = (const float*)d_in[13];
  const float* W_s1   = (const float*)d_in[14];
  const float* b_s1   = (const float*)d_in[15];
  const float* W_s2   = (const float*)d_in[16];
  const float* b_s2   = (const float*)d_in[17];

  float* out = (float*)d_out;
  float* out_pf     = out;                 // [64,8,256]
  float* out_pos    = out + 131072;        // [64,8,2]
  float* out_assign = out + 132096;        // [64,4096,8]
  float* out_sal    = out + 2229248;       // [64,8]
  float* out_feat   = out + 2229760;       // [64,4096,256]

  char* ws = (char*)d_ws;
  unsigned short* wT  = (unsigned short*)ws;               // 196608 B
  float* protoN       = (float*)(ws + 196608);             // 8192 B
  unsigned short* pbf = (unsigned short*)(ws + 204800);    // 8192 B
  float* acc_part     = (float*)(ws + 262144);             // 524288 B
  float* acc_mass     = (float*)(ws + 786432);             // 2048 B
  float* acc_pos      = (float*)(ws + 788480);             // 4096 B
  float* part_partial = (float*)(ws + 1048576);            // 33554432 B
  float* mp_partial   = (float*)(ws + 1048576 + 33554432); // 524288 B

  const size_t need_part = 1048576ull + 33554432ull + 524288ull;
  const int use_part = (ws_size >= need_part) ? 1 : 0;

  if (!use_part) hipMemsetAsync(ws + 262144, 0, 530432, stream);
  k_setup<<<385, 256, 0, stream>>>(W_proj, wT, proto, protoN, pbf);
  k_fused<<<4096, 512, 0, stream>>>(patch, b_proj, g1, beta1, wT, pbf,
                                    out_feat, out_assign,
                                    part_partial, mp_partial,
                                    acc_part, acc_mass, acc_pos, use_part);
  if (use_part) k_reduce<<<512, 256, 0, stream>>>(part_partial, acc_part);
  k_final<<<64, 256, 0, stream>>>(mp_partial, acc_part, acc_mass, acc_pos,
                                  g2, beta2, W_r1, b_r1, W_r2, b_r2,
                                  W_s1, b_s1, W_s2, b_s2,
                                  out_pf, out_pos, out_sal, use_part);
}

// Round 15
// 282.030 us; speedup vs baseline: 1.3508x; 1.3508x over previous
//
#include <hip/hip_runtime.h>
#include <hip/hip_bf16.h>
#include <stdint.h>
#include <stddef.h>

#define DF 384
#define DP 256
#define NPROT 8
#define NPB 4096
#define KSTEPS 12

typedef __attribute__((ext_vector_type(8))) short bf16x8;
typedef __attribute__((ext_vector_type(4))) short bf16x4;
typedef __attribute__((ext_vector_type(4))) float f32x4;

typedef const __attribute__((address_space(1))) unsigned char as1_u8;
typedef __attribute__((address_space(3))) unsigned char as3_u8;

static __device__ __forceinline__ short f2bf(float f) {
  __hip_bfloat16 h(f);
  return *reinterpret_cast<short*>(&h);
}
// fast GELU: NaN-safe, |err| ~1e-3 << 0.112 budget (validated R9-R14: absmax 0.03125)
static __device__ __forceinline__ float gelu_f(float x) {
  float x3 = x * x * x;
  float t = __expf(1.5957691216057308f * fmaf(0.044715f, x3, x));
  return x - x / (t + 1.0f);
}

static __device__ __forceinline__ f32x4 mfma16x16x16_bf16(bf16x4 a, bf16x4 b, f32x4 c) {
#if __has_builtin(__builtin_amdgcn_mfma_f32_16x16x16bf16_1k)
  return __builtin_amdgcn_mfma_f32_16x16x16bf16_1k(a, b, c, 0, 0, 0);
#else
  asm volatile("v_mfma_f32_16x16x16_bf16 %0, %1, %2, %0" : "+v"(c) : "v"(a), "v"(b));
  return c;
#endif
}

// ---------- setup: wT (bf16 W_projT) + protoN + proto B-fragments ----------
__global__ __launch_bounds__(256) void k_setup(const float* __restrict__ W,
                                               unsigned short* __restrict__ wT,
                                               const float* __restrict__ P,
                                               float* __restrict__ PN,
                                               unsigned short* __restrict__ pb) {
  if (blockIdx.x < 384) {
    int e = blockIdx.x * 256 + threadIdx.x;
    int c = e / DF;
    int k = e - c * DF;
    wT[e] = (unsigned short)f2bf(W[k * DP + c]);
  } else {
    __shared__ float s_red[4];
    __shared__ float s_pn[NPROT][DP];
    const int tid = threadIdx.x;
    const int lane = tid & 63, wave = tid >> 6;
    for (int r = 0; r < NPROT; r++) {
      float x = P[r * DP + tid];
      float q = x * x;
      #pragma unroll
      for (int d = 1; d < 64; d <<= 1) q += __shfl_xor(q, d);
      if (lane == 0) s_red[wave] = q;
      __syncthreads();
      float ss = s_red[0] + s_red[1] + s_red[2] + s_red[3];
      float v = x / fmaxf(sqrtf(ss), 1e-12f);
      PN[r * DP + tid] = v;
      s_pn[r][tid] = v;
      __syncthreads();
    }
    for (int i = tid; i < 512; i += 256) {
      int step = i >> 6, l = i & 63;
      int k = l & 15, g = l >> 4;
      bf16x8 v;
      #pragma unroll
      for (int j = 0; j < 8; j++) {
        int d = step * 32 + g * 8 + j;
        v[j] = (k < NPROT) ? f2bf(s_pn[k][d]) : (short)0;
      }
      *(bf16x8*)(pb + (size_t)i * 8) = v;
    }
  }
}

// ---------- fused (R12 verbatim, 251 us proven): GEMM+LN+GELU+feat+sim+part ----
__global__ __launch_bounds__(256, 3) void k_fused(
    const float* __restrict__ patch,
    const float* __restrict__ bias,
    const float* __restrict__ g1,
    const float* __restrict__ beta1,
    const unsigned short* __restrict__ wT,
    const unsigned short* __restrict__ pb,
    float* __restrict__ out_feat,
    float* __restrict__ out_assign,
    float* __restrict__ part_partial,
    float* __restrict__ mp_partial,
    float* __restrict__ acc_part,
    float* __restrict__ acc_mass,
    float* __restrict__ acc_pos,
    int use_part) {
  __shared__ __align__(16) unsigned char Bbuf[33792];
  __shared__ __align__(16) unsigned short s_pb[512 * 8];
  __shared__ float s_bias[DP], s_g1[DP], s_b1[DP];
  __shared__ float s_mp[4][3][NPROT];

  const int tid  = threadIdx.x;
  const int lane = tid & 63;
  const int wave = tid >> 6;
  const int mrow = lane & 15;
  const int kgrp = lane >> 4;

  const long long row0 = (long long)blockIdx.x * 64;
  const int b  = (int)(row0 >> 12);
  const int n0 = (int)(row0 & 4095);

  s_bias[tid] = bias[tid];
  s_g1[tid]   = g1[tid];
  s_b1[tid]   = beta1[tid];
  *(bf16x8*)(s_pb + (size_t)tid * 8)         = *(const bf16x8*)(pb + (size_t)tid * 8);
  *(bf16x8*)(s_pb + (size_t)(256 + tid) * 8) = *(const bf16x8*)(pb + (size_t)(256 + tid) * 8);

  #define STAGE(kt_, q_)                                                        \
    {                                                                           \
      _Pragma("unroll")                                                         \
      for (int i = 0; i < 4; i++) {                                             \
        int e   = i * 256 + tid;                                                \
        int col = e >> 2;                                                       \
        int t4  = e & 3;                                                        \
        int sub = t4 ^ ((col >> 1) & 3);                                        \
        const unsigned short* src = wT + col * DF + (kt_) * 32 + sub * 8;       \
        int lofs = __builtin_amdgcn_readfirstlane(                              \
            (q_) * 16384 + (i * 256 + wave * 64) * 16);                         \
        __builtin_amdgcn_global_load_lds((as1_u8*)(const void*)src,             \
                                         (as3_u8*)(void*)(Bbuf + lofs), 16, 0, 0); \
      }                                                                         \
    }

  STAGE(0, 0);
  const float* arow = patch + (size_t)(row0 + wave * 16 + mrow) * DF + kgrp * 8;
  bf16x8 afrag[KSTEPS];
  #pragma unroll
  for (int kt = 0; kt < KSTEPS; kt++) {
    float4 x0 = *(const float4*)(arow + kt * 32);
    float4 x1 = *(const float4*)(arow + kt * 32 + 4);
    bf16x8 a;
    a[0] = f2bf(x0.x); a[1] = f2bf(x0.y); a[2] = f2bf(x0.z); a[3] = f2bf(x0.w);
    a[4] = f2bf(x1.x); a[5] = f2bf(x1.y); a[6] = f2bf(x1.z); a[7] = f2bf(x1.w);
    afrag[kt] = a;
  }

  f32x4 acc[16];
  #pragma unroll
  for (int f = 0; f < 16; f++) acc[f] = (f32x4){0.f, 0.f, 0.f, 0.f};

  __syncthreads();   // prologue drain: buf0 ready, s_pb/s_bias visible

  const int lane_swz = mrow * 64 + (kgrp ^ ((mrow >> 1) & 3)) * 16;

  #pragma unroll
  for (int kt = 0; kt < KSTEPS; kt++) {
    if (kt + 1 < KSTEPS) STAGE(kt + 1, (kt + 1) & 1);   // in flight across MFMAs
    const unsigned char* bbase = Bbuf + (kt & 1) * 16384 + lane_swz;
    bf16x8 a = afrag[kt];
    #pragma unroll
    for (int f = 0; f < 16; f++) {
      bf16x8 bf = *(const bf16x8*)(bbase + f * 1024);
      acc[f] = __builtin_amdgcn_mfma_f32_16x16x32_bf16(a, bf, acc[f], 0, 0, 0);
    }
    asm volatile("s_waitcnt vmcnt(0) lgkmcnt(0)" ::: "memory");
    __builtin_amdgcn_s_barrier();
    __builtin_amdgcn_sched_barrier(0);
  }
  #undef STAGE

  // ---- bias + LayerNorm + GELU  (C layout: col=f*16+mrow, row=kgrp*4+r) ----
  #pragma unroll
  for (int f = 0; f < 16; f++) {
    const float bb = s_bias[f * 16 + mrow];
    #pragma unroll
    for (int r = 0; r < 4; r++) acc[f][r] += bb;
  }
  #pragma unroll
  for (int r = 0; r < 4; r++) {
    float s = 0.f, q = 0.f;
    #pragma unroll
    for (int f = 0; f < 16; f++) { float x = acc[f][r]; s += x; q += x * x; }
    #pragma unroll
    for (int d = 1; d < 16; d <<= 1) { s += __shfl_xor(s, d); q += __shfl_xor(q, d); }
    const float mean = s * (1.f / 256.f);
    const float var  = q * (1.f / 256.f) - mean * mean;
    const float rstd = rsqrtf(var + 1e-5f);
    #pragma unroll
    for (int f = 0; f < 16; f++) {
      const int col = f * 16 + mrow;
      float y = (acc[f][r] - mean) * rstd * s_g1[col] + s_b1[col];
      acc[f][r] = gelu_f(y);
    }
  }

  // ---- ss per row ----
  float ssn[4];
  #pragma unroll
  for (int r = 0; r < 4; r++) {
    float q2 = 0.f;
    #pragma unroll
    for (int f = 0; f < 16; f++) q2 += acc[f][r] * acc[f][r];
    #pragma unroll
    for (int d = 1; d < 16; d <<= 1) q2 += __shfl_xor(q2, d);
    ssn[r] = q2;
  }

  // ---- transpose halves: feat store + interleaved sim MFMA (pf from LDS) ----
  f32x4 cdot = (f32x4){0.f, 0.f, 0.f, 0.f};
  {
    float* s_tr = (float*)Bbuf;                   // [4][16][132]
    const int rr = lane >> 5;
    const int cc = (lane & 31) * 4;
    float* fb = out_feat + (size_t)(row0 + wave * 16) * DP;
    const int aoff = (wave * 16 + mrow) * 132 + kgrp * 8;
    #pragma unroll
    for (int p = 0; p < 2; p++) {
      #pragma unroll
      for (int fl = 0; fl < 8; fl++) {
        const int f = 8 * p + fl;
        #pragma unroll
        for (int r = 0; r < 4; r++)
          s_tr[(wave * 16 + kgrp * 4 + r) * 132 + fl * 16 + mrow] = acc[f][r];
      }
      #pragma unroll
      for (int i = 0; i < 8; i++) {
        const int row = i * 2 + rr;
        f32x4 v = *(const f32x4*)&s_tr[(wave * 16 + row) * 132 + cc];
        *(f32x4*)&fb[(size_t)row * DP + p * 128 + cc] = v;
      }
      #pragma unroll
      for (int s = 0; s < 4; s++) {
        float4 y0 = *(const float4*)&s_tr[aoff + s * 32];
        float4 y1 = *(const float4*)&s_tr[aoff + s * 32 + 4];
        bf16x8 a;
        a[0] = f2bf(y0.x); a[1] = f2bf(y0.y); a[2] = f2bf(y0.z); a[3] = f2bf(y0.w);
        a[4] = f2bf(y1.x); a[5] = f2bf(y1.y); a[6] = f2bf(y1.z); a[7] = f2bf(y1.w);
        bf16x8 pf = *(const bf16x8*)(s_pb + (size_t)((p * 4 + s) * 64 + lane) * 8);
        cdot = __builtin_amdgcn_mfma_f32_16x16x32_bf16(a, pf, cdot, 0, 0, 0);
      }
    }
  }

  // ---- softmax over k (k = mrow, lanes 8..15 masked) ----
  float asg[4];
  #pragma unroll
  for (int r = 0; r < 4; r++) {
    const float nrm = fmaxf(sqrtf(ssn[r]), 1e-12f);
    float lg = (mrow < NPROT) ? (cdot[r] / nrm) * (1.f / 0.07f) : -1e30f;
    float mx = lg;
    #pragma unroll
    for (int d = 1; d < 16; d <<= 1) mx = fmaxf(mx, __shfl_xor(mx, d));
    float e = __expf(lg - mx);
    float se = e;
    #pragma unroll
    for (int d = 1; d < 16; d <<= 1) se += __shfl_xor(se, d);
    asg[r] = e / se;
  }

  // ---- assign writes + mass/pos ----
  float pm = 0.f, px = 0.f, py = 0.f;
  #pragma unroll
  for (int r = 0; r < 4; r++) {
    const int n = n0 + wave * 16 + kgrp * 4 + r;
    if (mrow < NPROT)
      out_assign[((size_t)b * NPB + n) * NPROT + mrow] = asg[r];
    const float cx = (float)(n & 63) * (1.f / 63.f);
    const float cy = (float)(n >> 6) * (1.f / 63.f);
    pm += asg[r]; px += asg[r] * cx; py += asg[r] * cy;
  }
  pm += __shfl_xor(pm, 16); pm += __shfl_xor(pm, 32);
  px += __shfl_xor(px, 16); px += __shfl_xor(px, 32);
  py += __shfl_xor(py, 16); py += __shfl_xor(py, 32);
  if (lane < NPROT) {
    s_mp[wave][0][lane] = pm;
    s_mp[wave][1][lane] = px;
    s_mp[wave][2][lane] = py;
  }

  __syncthreads();   // all waves done reading s_tr; Bbuf becomes s_partw

  // ---- part via MFMA 16x16x16: B-frag = acc directly ----
  {
    float* s_partw = (float*)Bbuf;   // [4][8][256]
    bf16x4 a4;
    #pragma unroll
    for (int j = 0; j < 4; j++) a4[j] = f2bf(asg[j]);
    #pragma unroll
    for (int f = 0; f < 16; f++) {
      bf16x4 b4;
      #pragma unroll
      for (int j = 0; j < 4; j++) b4[j] = f2bf(acc[f][j]);
      f32x4 c = mfma16x16x16_bf16(a4, b4, (f32x4){0.f, 0.f, 0.f, 0.f});
      if (kgrp < 2) {
        #pragma unroll
        for (int r = 0; r < 4; r++)
          s_partw[((wave * 8 + kgrp * 4 + r)) * 256 + f * 16 + mrow] = c[r];
      }
    }
  }
  __syncthreads();

  // ---- cross-wave combine + flush ----
  {
    const float* s_partw = (const float*)Bbuf;
    float pr[NPROT];
    #pragma unroll
    for (int k = 0; k < NPROT; k++)
      pr[k] = s_partw[(0 * 8 + k) * 256 + tid] + s_partw[(1 * 8 + k) * 256 + tid] +
              s_partw[(2 * 8 + k) * 256 + tid] + s_partw[(3 * 8 + k) * 256 + tid];

    if (use_part) {
      float* pp = part_partial + (size_t)blockIdx.x * 2048;
      #pragma unroll
      for (int k = 0; k < NPROT; k++) pp[k * 256 + tid] = pr[k];
      if (tid < 24) {
        const int v = tid >> 3, k = tid & 7;
        float s = s_mp[0][v][k] + s_mp[1][v][k] + s_mp[2][v][k] + s_mp[3][v][k];
        mp_partial[(size_t)blockIdx.x * 32 + v * 8 + k] = s;
      }
    } else {
      float* gp = acc_part + (size_t)b * (NPROT * DP);
      #pragma unroll
      for (int k = 0; k < NPROT; k++) atomicAdd(&gp[k * 256 + tid], pr[k]);
      if (tid < 24) {
        const int v = tid >> 3, k = tid & 7;
        float s = s_mp[0][v][k] + s_mp[1][v][k] + s_mp[2][v][k] + s_mp[3][v][k];
        if (v == 0) atomicAdd(&acc_mass[b * NPROT + k], s);
        else        atomicAdd(&acc_pos[(b * NPROT + k) * 2 + (v - 1)], s);
      }
    }
  }
}

// ---------- parallel reduction of part partials ----------
__global__ __launch_bounds__(256) void k_reduce(const float* __restrict__ pp,
                                                float* __restrict__ acc_part) {
  const int b = blockIdx.x >> 3;
  const int j = blockIdx.x & 7;
  const int col = j * 256 + threadIdx.x;
  const float* base = pp + (size_t)b * 64 * 2048 + col;
  float a0 = 0.f, a1 = 0.f, a2 = 0.f, a3 = 0.f;
  #pragma unroll
  for (int p = 0; p < 64; p += 4) {
    a0 += base[(size_t)p * 2048];
    a1 += base[(size_t)(p + 1) * 2048];
    a2 += base[(size_t)(p + 2) * 2048];
    a3 += base[(size_t)(p + 3) * 2048];
  }
  acc_part[(size_t)b * 2048 + col] = (a0 + a1) + (a2 + a3);
}

// ---------- per-batch finalize: 512 threads, split serial chains ----------
__global__ __launch_bounds__(512) void k_final(
    const float* __restrict__ mp_partial,
    const float* __restrict__ acc_part, const float* __restrict__ acc_mass,
    const float* __restrict__ acc_pos,
    const float* __restrict__ g2, const float* __restrict__ beta2,
    const float* __restrict__ W_r1, const float* __restrict__ b_r1,
    const float* __restrict__ W_r2, const float* __restrict__ b_r2,
    const float* __restrict__ W_s1, const float* __restrict__ b_s1,
    const float* __restrict__ W_s2, const float* __restrict__ b_s2,
    float* __restrict__ out_pf, float* __restrict__ out_pos, float* __restrict__ out_sal,
    int use_part) {
  __shared__ float s_pf[8 * DP];
  __shared__ float s_h[8 * DP];
  __shared__ float s_t[8 * 512];
  __shared__ float s_pff[8 * DP];
  __shared__ float s_s1v[8 * 64];
  __shared__ float s_m[8];
  __shared__ float s_mpred[24];
  __shared__ float s_r2p[8 * DP];
  __shared__ float s_s1p[8][8][64];
  const int b = blockIdx.x;
  const int tid = threadIdx.x;
  const int lane = tid & 63, wave = tid >> 6;

  // ---- mass/pos reduction (parallel: 24 (v,k) pairs x 16 threads) ----
  if (use_part) {
    if (tid < 384) {
      const int vk = tid >> 4;        // 0..23
      const int jt = tid & 15;        // 0..15
      const int v = vk >> 3, k = vk & 7;
      const float* q = mp_partial + ((size_t)b * 64 + jt * 4) * 32 + v * 8 + k;
      float part = q[0] + q[32] + q[64] + q[96];   // j-stride = 32 floats
      #pragma unroll
      for (int d = 1; d < 16; d <<= 1) part += __shfl_xor(part, d);
      if (jt == 0) s_mpred[vk] = part;
    }
    __syncthreads();
    if (tid < 8) s_m[tid] = fmaxf(s_mpred[tid], 1e-6f);
    __syncthreads();
    if (tid < 16) {
      const int k = tid >> 1, xy = tid & 1;
      out_pos[b * 16 + tid] = s_mpred[(xy + 1) * 8 + k] / s_m[k];
    }
  } else {
    if (tid < 8) s_m[tid] = fmaxf(acc_mass[b * 8 + tid], 1e-6f);
    if (tid >= 64 && tid < 80) {
      int t = tid - 64;
      out_pos[b * 16 + t] = acc_pos[b * 16 + t] / fmaxf(acc_mass[b * 8 + (t >> 1)], 1e-6f);
    }
    __syncthreads();
  }
  __syncthreads();

  #pragma unroll
  for (int i = 0; i < 4; i++) {
    const int idx = i * 512 + tid;
    s_pf[idx] = acc_part[(size_t)b * 2048 + idx] / s_m[idx >> 8];
  }
  __syncthreads();

  // ---- LayerNorm: one row per wave (8 rows concurrent) ----
  {
    const int r = wave;
    f32x4 x = *(const f32x4*)&s_pf[r * DP + lane * 4];
    float s = x[0] + x[1] + x[2] + x[3];
    float q = x[0] * x[0] + x[1] * x[1] + x[2] * x[2] + x[3] * x[3];
    #pragma unroll
    for (int d = 1; d < 64; d <<= 1) { s += __shfl_xor(s, d); q += __shfl_xor(q, d); }
    const float mean = s * (1.f / 256.f);
    const float var  = q * (1.f / 256.f) - mean * mean;
    const float rstd = rsqrtf(var + 1e-5f);
    #pragma unroll
    for (int j = 0; j < 4; j++) {
      const int col = lane * 4 + j;
      s_h[r * DP + col] = (x[j] - mean) * rstd * g2[col] + beta2[col];
    }
  }
  __syncthreads();

  // ---- r1: 512 outputs in parallel ----
  {
    const int o = tid;
    float a[8];
    #pragma unroll
    for (int r = 0; r < 8; r++) a[r] = 0.f;
    #pragma unroll 8
    for (int c = 0; c < DP; c++) {
      const float w = W_r1[c * 512 + o];
      #pragma unroll
      for (int r = 0; r < 8; r++) a[r] += s_h[r * DP + c] * w;
    }
    const float bb = b_r1[o];
    #pragma unroll
    for (int r = 0; r < 8; r++) s_t[r * 512 + o] = gelu_f(a[r] + bb);
  }
  __syncthreads();

  // ---- r2: c split across two 256-halves, LDS combine + residual ----
  {
    const int g = tid >> 8, o = tid & 255;
    float a[8];
    #pragma unroll
    for (int r = 0; r < 8; r++) a[r] = 0.f;
    #pragma unroll 8
    for (int cc = 0; cc < 256; cc++) {
      const int c = g * 256 + cc;
      const float w = W_r2[c * DP + o];
      #pragma unroll
      for (int r = 0; r < 8; r++) a[r] += s_t[r * 512 + c] * w;
    }
    if (g) {
      #pragma unroll
      for (int r = 0; r < 8; r++) s_r2p[r * DP + o] = a[r];
    }
    __syncthreads();
    if (!g) {
      const float bb = b_r2[o];
      #pragma unroll
      for (int r = 0; r < 8; r++) {
        float v = s_pf[r * DP + o] + a[r] + s_r2p[r * DP + o] + bb;
        s_pff[r * DP + o] = v;
        out_pf[(size_t)b * 2048 + r * DP + o] = v;
      }
    }
  }
  __syncthreads();

  // ---- s1: c split across eight 32-chunks, LDS combine ----
  {
    const int o = tid & 63, g = tid >> 6;
    float a[8];
    #pragma unroll
    for (int r = 0; r < 8; r++) a[r] = 0.f;
    #pragma unroll 8
    for (int cc = 0; cc < 32; cc++) {
      const int c = g * 32 + cc;
      const float w = W_s1[c * 64 + o];
      #pragma unroll
      for (int r = 0; r < 8; r++) a[r] += s_pff[r * DP + c] * w;
    }
    #pragma unroll
    for (int r = 0; r < 8; r++) s_s1p[g][r][o] = a[r];
  }
  __syncthreads();
  {
    const int r = tid >> 6, o = tid & 63;
    float a = 0.f;
    #pragma unroll
    for (int g = 0; g < 8; g++) a += s_s1p[g][r][o];
    s_s1v[r * 64 + o] = gelu_f(a + b_s1[o]);
  }
  __syncthreads();

  // ---- s2 + sigmoid ----
  if (tid < 8) {
    float a = 0.f;
    for (int c = 0; c < 64; c++) a += s_s1v[tid * 64 + c] * W_s2[c];
    a += b_s2[0];
    out_sal[b * 8 + tid] = 1.f / (1.f + __expf(-a));
  }
}

extern "C" void kernel_launch(void* const* d_in, const int* in_sizes, int n_in,
                              void* d_out, int out_size, void* d_ws, size_t ws_size,
                              hipStream_t stream) {
  (void)in_sizes; (void)n_in; (void)out_size;
  const float* patch  = (const float*)d_in[0];
  const float* W_proj = (const float*)d_in[3];
  const float* b_proj = (const float*)d_in[4];
  const float* g1     = (const float*)d_in[5];
  const float* beta1  = (const float*)d_in[6];
  const float* proto  = (const float*)d_in[7];
  const float* g2     = (const float*)d_in[8];
  const float* beta2  = (const float*)d_in[9];
  const float* W_r1   = (const float*)d_in[10];
  const float* b_r1   = (const float*)d_in[11];
  const float* W_r2   = (const float*)d_in[12];
  const float* b_r2   = (const float*)d_in[13];
  const float* W_s1   = (const float*)d_in[14];
  const float* b_s1   = (const float*)d_in[15];
  const float* W_s2   = (const float*)d_in[16];
  const float* b_s2   = (const float*)d_in[17];

  float* out = (float*)d_out;
  float* out_pf     = out;                 // [64,8,256]
  float* out_pos    = out + 131072;        // [64,8,2]
  float* out_assign = out + 132096;        // [64,4096,8]
  float* out_sal    = out + 2229248;       // [64,8]
  float* out_feat   = out + 2229760;       // [64,4096,256]

  char* ws = (char*)d_ws;
  unsigned short* wT  = (unsigned short*)ws;               // 196608 B
  float* protoN       = (float*)(ws + 196608);             // 8192 B
  unsigned short* pbf = (unsigned short*)(ws + 204800);    // 8192 B
  float* acc_part     = (float*)(ws + 262144);             // 524288 B
  float* acc_mass     = (float*)(ws + 786432);             // 2048 B
  float* acc_pos      = (float*)(ws + 788480);             // 4096 B
  float* part_partial = (float*)(ws + 1048576);            // 33554432 B
  float* mp_partial   = (float*)(ws + 1048576 + 33554432); // 524288 B

  const size_t need_part = 1048576ull + 33554432ull + 524288ull;
  const int use_part = (ws_size >= need_part) ? 1 : 0;

  if (!use_part) hipMemsetAsync(ws + 262144, 0, 530432, stream);
  k_setup<<<385, 256, 0, stream>>>(W_proj, wT, proto, protoN, pbf);
  k_fused<<<4096, 256, 0, stream>>>(patch, b_proj, g1, beta1, wT, pbf,
                                    out_feat, out_assign,
                                    part_partial, mp_partial,
                                    acc_part, acc_mass, acc_pos, use_part);
  if (use_part) k_reduce<<<512, 256, 0, stream>>>(part_partial, acc_part);
  k_final<<<64, 512, 0, stream>>>(mp_partial, acc_part, acc_mass, acc_pos,
                                  g2, beta2, W_r1, b_r1, W_r2, b_r2,
                                  W_s1, b_s1, W_s2, b_s2,
                                  out_pf, out_pos, out_sal, use_part);
}

// Round 16
// 277.488 us; speedup vs baseline: 1.3729x; 1.0164x over previous
//
#include <hip/hip_runtime.h>
#include <hip/hip_bf16.h>
#include <stdint.h>
#include <stddef.h>

#define DF 384
#define DP 256
#define NPROT 8
#define NPB 4096
#define KSTEPS 12

typedef __attribute__((ext_vector_type(8))) short bf16x8;
typedef __attribute__((ext_vector_type(4))) short bf16x4;
typedef __attribute__((ext_vector_type(4))) float f32x4;

typedef const __attribute__((address_space(1))) unsigned char as1_u8;
typedef __attribute__((address_space(3))) unsigned char as3_u8;

static __device__ __forceinline__ short f2bf(float f) {
  __hip_bfloat16 h(f);
  return *reinterpret_cast<short*>(&h);
}
static __device__ __forceinline__ float bf2f(unsigned short u) {
  return __uint_as_float(((unsigned)u) << 16);
}
// fast GELU: NaN-safe, |err| ~1e-3 << 0.112 budget (validated R9-R15: absmax 0.03125)
static __device__ __forceinline__ float gelu_f(float x) {
  float x3 = x * x * x;
  float t = __expf(1.5957691216057308f * fmaf(0.044715f, x3, x));
  return x - x / (t + 1.0f);
}

static __device__ __forceinline__ f32x4 mfma16x16x16_bf16(bf16x4 a, bf16x4 b, f32x4 c) {
#if __has_builtin(__builtin_amdgcn_mfma_f32_16x16x16bf16_1k)
  return __builtin_amdgcn_mfma_f32_16x16x16bf16_1k(a, b, c, 0, 0, 0);
#else
  asm volatile("v_mfma_f32_16x16x16_bf16 %0, %1, %2, %0" : "+v"(c) : "v"(a), "v"(b));
  return c;
#endif
}

// ---------- setup: wT (bf16 W_projT) + protoN + proto B-fragments ----------
__global__ __launch_bounds__(256) void k_setup(const float* __restrict__ W,
                                               unsigned short* __restrict__ wT,
                                               const float* __restrict__ P,
                                               float* __restrict__ PN,
                                               unsigned short* __restrict__ pb) {
  if (blockIdx.x < 384) {
    int e = blockIdx.x * 256 + threadIdx.x;
    int c = e / DF;
    int k = e - c * DF;
    wT[e] = (unsigned short)f2bf(W[k * DP + c]);
  } else {
    __shared__ float s_red[4];
    __shared__ float s_pn[NPROT][DP];
    const int tid = threadIdx.x;
    const int lane = tid & 63, wave = tid >> 6;
    for (int r = 0; r < NPROT; r++) {
      float x = P[r * DP + tid];
      float q = x * x;
      #pragma unroll
      for (int d = 1; d < 64; d <<= 1) q += __shfl_xor(q, d);
      if (lane == 0) s_red[wave] = q;
      __syncthreads();
      float ss = s_red[0] + s_red[1] + s_red[2] + s_red[3];
      float v = x / fmaxf(sqrtf(ss), 1e-12f);
      PN[r * DP + tid] = v;
      s_pn[r][tid] = v;
      __syncthreads();
    }
    for (int i = tid; i < 512; i += 256) {
      int step = i >> 6, l = i & 63;
      int k = l & 15, g = l >> 4;
      bf16x8 v;
      #pragma unroll
      for (int j = 0; j < 8; j++) {
        int d = step * 32 + g * 8 + j;
        v[j] = (k < NPROT) ? f2bf(s_pn[k][d]) : (short)0;
      }
      *(bf16x8*)(pb + (size_t)i * 8) = v;
    }
  }
}

// ---------- fused (R12 structure, 251 us proven): GEMM+LN+GELU+feat+sim+part ----
__global__ __launch_bounds__(256, 3) void k_fused(
    const float* __restrict__ patch,
    const float* __restrict__ bias,
    const float* __restrict__ g1,
    const float* __restrict__ beta1,
    const unsigned short* __restrict__ wT,
    const unsigned short* __restrict__ pb,
    float* __restrict__ out_feat,
    float* __restrict__ out_assign,
    unsigned short* __restrict__ part_partial,   // bf16 partials (R16)
    float* __restrict__ mp_partial,
    float* __restrict__ acc_part,
    float* __restrict__ acc_mass,
    float* __restrict__ acc_pos,
    int use_part) {
  __shared__ __align__(16) unsigned char Bbuf[33792];
  __shared__ __align__(16) unsigned short s_pb[512 * 8];
  __shared__ float s_bias[DP], s_g1[DP], s_b1[DP];
  __shared__ float s_mp[4][3][NPROT];

  const int tid  = threadIdx.x;
  const int lane = tid & 63;
  const int wave = tid >> 6;
  const int mrow = lane & 15;
  const int kgrp = lane >> 4;

  const long long row0 = (long long)blockIdx.x * 64;
  const int b  = (int)(row0 >> 12);
  const int n0 = (int)(row0 & 4095);

  s_bias[tid] = bias[tid];
  s_g1[tid]   = g1[tid];
  s_b1[tid]   = beta1[tid];
  *(bf16x8*)(s_pb + (size_t)tid * 8)         = *(const bf16x8*)(pb + (size_t)tid * 8);
  *(bf16x8*)(s_pb + (size_t)(256 + tid) * 8) = *(const bf16x8*)(pb + (size_t)(256 + tid) * 8);

  #define STAGE(kt_, q_)                                                        \
    {                                                                           \
      _Pragma("unroll")                                                         \
      for (int i = 0; i < 4; i++) {                                             \
        int e   = i * 256 + tid;                                                \
        int col = e >> 2;                                                       \
        int t4  = e & 3;                                                        \
        int sub = t4 ^ ((col >> 1) & 3);                                        \
        const unsigned short* src = wT + col * DF + (kt_) * 32 + sub * 8;       \
        int lofs = __builtin_amdgcn_readfirstlane(                              \
            (q_) * 16384 + (i * 256 + wave * 64) * 16);                         \
        __builtin_amdgcn_global_load_lds((as1_u8*)(const void*)src,             \
                                         (as3_u8*)(void*)(Bbuf + lofs), 16, 0, 0); \
      }                                                                         \
    }

  STAGE(0, 0);
  const float* arow = patch + (size_t)(row0 + wave * 16 + mrow) * DF + kgrp * 8;
  bf16x8 afrag[KSTEPS];
  #pragma unroll
  for (int kt = 0; kt < KSTEPS; kt++) {
    float4 x0 = *(const float4*)(arow + kt * 32);
    float4 x1 = *(const float4*)(arow + kt * 32 + 4);
    bf16x8 a;
    a[0] = f2bf(x0.x); a[1] = f2bf(x0.y); a[2] = f2bf(x0.z); a[3] = f2bf(x0.w);
    a[4] = f2bf(x1.x); a[5] = f2bf(x1.y); a[6] = f2bf(x1.z); a[7] = f2bf(x1.w);
    afrag[kt] = a;
  }

  f32x4 acc[16];
  #pragma unroll
  for (int f = 0; f < 16; f++) acc[f] = (f32x4){0.f, 0.f, 0.f, 0.f};

  __syncthreads();   // prologue drain: buf0 ready, s_pb/s_bias visible

  const int lane_swz = mrow * 64 + (kgrp ^ ((mrow >> 1) & 3)) * 16;

  #pragma unroll
  for (int kt = 0; kt < KSTEPS; kt++) {
    if (kt + 1 < KSTEPS) STAGE(kt + 1, (kt + 1) & 1);   // in flight across MFMAs
    const unsigned char* bbase = Bbuf + (kt & 1) * 16384 + lane_swz;
    bf16x8 a = afrag[kt];
    #pragma unroll
    for (int f = 0; f < 16; f++) {
      bf16x8 bf = *(const bf16x8*)(bbase + f * 1024);
      acc[f] = __builtin_amdgcn_mfma_f32_16x16x32_bf16(a, bf, acc[f], 0, 0, 0);
    }
    asm volatile("s_waitcnt vmcnt(0) lgkmcnt(0)" ::: "memory");
    __builtin_amdgcn_s_barrier();
    __builtin_amdgcn_sched_barrier(0);
  }
  #undef STAGE

  // ---- bias + LayerNorm + GELU  (C layout: col=f*16+mrow, row=kgrp*4+r) ----
  #pragma unroll
  for (int f = 0; f < 16; f++) {
    const float bb = s_bias[f * 16 + mrow];
    #pragma unroll
    for (int r = 0; r < 4; r++) acc[f][r] += bb;
  }
  #pragma unroll
  for (int r = 0; r < 4; r++) {
    float s = 0.f, q = 0.f;
    #pragma unroll
    for (int f = 0; f < 16; f++) { float x = acc[f][r]; s += x; q += x * x; }
    #pragma unroll
    for (int d = 1; d < 16; d <<= 1) { s += __shfl_xor(s, d); q += __shfl_xor(q, d); }
    const float mean = s * (1.f / 256.f);
    const float var  = q * (1.f / 256.f) - mean * mean;
    const float rstd = rsqrtf(var + 1e-5f);
    #pragma unroll
    for (int f = 0; f < 16; f++) {
      const int col = f * 16 + mrow;
      float y = (acc[f][r] - mean) * rstd * s_g1[col] + s_b1[col];
      acc[f][r] = gelu_f(y);
    }
  }

  // ---- ss per row ----
  float ssn[4];
  #pragma unroll
  for (int r = 0; r < 4; r++) {
    float q2 = 0.f;
    #pragma unroll
    for (int f = 0; f < 16; f++) q2 += acc[f][r] * acc[f][r];
    #pragma unroll
    for (int d = 1; d < 16; d <<= 1) q2 += __shfl_xor(q2, d);
    ssn[r] = q2;
  }

  // ---- transpose halves: feat store + interleaved sim MFMA (pf from LDS) ----
  f32x4 cdot = (f32x4){0.f, 0.f, 0.f, 0.f};
  {
    float* s_tr = (float*)Bbuf;                   // [4][16][132]
    const int rr = lane >> 5;
    const int cc = (lane & 31) * 4;
    float* fb = out_feat + (size_t)(row0 + wave * 16) * DP;
    const int aoff = (wave * 16 + mrow) * 132 + kgrp * 8;
    #pragma unroll
    for (int p = 0; p < 2; p++) {
      #pragma unroll
      for (int fl = 0; fl < 8; fl++) {
        const int f = 8 * p + fl;
        #pragma unroll
        for (int r = 0; r < 4; r++)
          s_tr[(wave * 16 + kgrp * 4 + r) * 132 + fl * 16 + mrow] = acc[f][r];
      }
      #pragma unroll
      for (int i = 0; i < 8; i++) {
        const int row = i * 2 + rr;
        f32x4 v = *(const f32x4*)&s_tr[(wave * 16 + row) * 132 + cc];
        *(f32x4*)&fb[(size_t)row * DP + p * 128 + cc] = v;
      }
      #pragma unroll
      for (int s = 0; s < 4; s++) {
        float4 y0 = *(const float4*)&s_tr[aoff + s * 32];
        float4 y1 = *(const float4*)&s_tr[aoff + s * 32 + 4];
        bf16x8 a;
        a[0] = f2bf(y0.x); a[1] = f2bf(y0.y); a[2] = f2bf(y0.z); a[3] = f2bf(y0.w);
        a[4] = f2bf(y1.x); a[5] = f2bf(y1.y); a[6] = f2bf(y1.z); a[7] = f2bf(y1.w);
        bf16x8 pf = *(const bf16x8*)(s_pb + (size_t)((p * 4 + s) * 64 + lane) * 8);
        cdot = __builtin_amdgcn_mfma_f32_16x16x32_bf16(a, pf, cdot, 0, 0, 0);
      }
    }
  }

  // ---- softmax over k (k = mrow, lanes 8..15 masked) ----
  float asg[4];
  #pragma unroll
  for (int r = 0; r < 4; r++) {
    const float nrm = fmaxf(sqrtf(ssn[r]), 1e-12f);
    float lg = (mrow < NPROT) ? (cdot[r] / nrm) * (1.f / 0.07f) : -1e30f;
    float mx = lg;
    #pragma unroll
    for (int d = 1; d < 16; d <<= 1) mx = fmaxf(mx, __shfl_xor(mx, d));
    float e = __expf(lg - mx);
    float se = e;
    #pragma unroll
    for (int d = 1; d < 16; d <<= 1) se += __shfl_xor(se, d);
    asg[r] = e / se;
  }

  // ---- assign writes + mass/pos ----
  float pm = 0.f, px = 0.f, py = 0.f;
  #pragma unroll
  for (int r = 0; r < 4; r++) {
    const int n = n0 + wave * 16 + kgrp * 4 + r;
    if (mrow < NPROT)
      out_assign[((size_t)b * NPB + n) * NPROT + mrow] = asg[r];
    const float cx = (float)(n & 63) * (1.f / 63.f);
    const float cy = (float)(n >> 6) * (1.f / 63.f);
    pm += asg[r]; px += asg[r] * cx; py += asg[r] * cy;
  }
  pm += __shfl_xor(pm, 16); pm += __shfl_xor(pm, 32);
  px += __shfl_xor(px, 16); px += __shfl_xor(px, 32);
  py += __shfl_xor(py, 16); py += __shfl_xor(py, 32);
  if (lane < NPROT) {
    s_mp[wave][0][lane] = pm;
    s_mp[wave][1][lane] = px;
    s_mp[wave][2][lane] = py;
  }

  __syncthreads();   // all waves done reading s_tr; Bbuf becomes s_partw

  // ---- part via MFMA 16x16x16: B-frag = acc directly ----
  {
    float* s_partw = (float*)Bbuf;   // [4][8][256]
    bf16x4 a4;
    #pragma unroll
    for (int j = 0; j < 4; j++) a4[j] = f2bf(asg[j]);
    #pragma unroll
    for (int f = 0; f < 16; f++) {
      bf16x4 b4;
      #pragma unroll
      for (int j = 0; j < 4; j++) b4[j] = f2bf(acc[f][j]);
      f32x4 c = mfma16x16x16_bf16(a4, b4, (f32x4){0.f, 0.f, 0.f, 0.f});
      if (kgrp < 2) {
        #pragma unroll
        for (int r = 0; r < 4; r++)
          s_partw[((wave * 8 + kgrp * 4 + r)) * 256 + f * 16 + mrow] = c[r];
      }
    }
  }
  __syncthreads();

  // ---- cross-wave combine + flush (bf16 partials) ----
  {
    const float* s_partw = (const float*)Bbuf;
    float pr[NPROT];
    #pragma unroll
    for (int k = 0; k < NPROT; k++)
      pr[k] = s_partw[(0 * 8 + k) * 256 + tid] + s_partw[(1 * 8 + k) * 256 + tid] +
              s_partw[(2 * 8 + k) * 256 + tid] + s_partw[(3 * 8 + k) * 256 + tid];

    if (use_part) {
      unsigned short* pp = part_partial + (size_t)blockIdx.x * 2048;
      #pragma unroll
      for (int k = 0; k < NPROT; k++) pp[k * 256 + tid] = (unsigned short)f2bf(pr[k]);
      if (tid < 24) {
        const int v = tid >> 3, k = tid & 7;
        float s = s_mp[0][v][k] + s_mp[1][v][k] + s_mp[2][v][k] + s_mp[3][v][k];
        mp_partial[(size_t)blockIdx.x * 32 + v * 8 + k] = s;
      }
    } else {
      float* gp = acc_part + (size_t)b * (NPROT * DP);
      #pragma unroll
      for (int k = 0; k < NPROT; k++) atomicAdd(&gp[k * 256 + tid], pr[k]);
      if (tid < 24) {
        const int v = tid >> 3, k = tid & 7;
        float s = s_mp[0][v][k] + s_mp[1][v][k] + s_mp[2][v][k] + s_mp[3][v][k];
        if (v == 0) atomicAdd(&acc_mass[b * NPROT + k], s);
        else        atomicAdd(&acc_pos[(b * NPROT + k) * 2 + (v - 1)], s);
      }
    }
  }
}

// ---------- parallel reduction of bf16 part partials ----------
__global__ __launch_bounds__(256) void k_reduce(const unsigned short* __restrict__ pp,
                                                float* __restrict__ acc_part) {
  const int b = blockIdx.x >> 3;
  const int j = blockIdx.x & 7;
  const int col = j * 256 + threadIdx.x;
  const unsigned short* base = pp + (size_t)b * 64 * 2048 + col;
  float a0 = 0.f, a1 = 0.f, a2 = 0.f, a3 = 0.f;
  #pragma unroll
  for (int p = 0; p < 64; p += 4) {
    a0 += bf2f(base[(size_t)p * 2048]);
    a1 += bf2f(base[(size_t)(p + 1) * 2048]);
    a2 += bf2f(base[(size_t)(p + 2) * 2048]);
    a3 += bf2f(base[(size_t)(p + 3) * 2048]);
  }
  acc_part[(size_t)b * 2048 + col] = (a0 + a1) + (a2 + a3);
}

// ---------- per-batch finalize: 512 threads, split serial chains (R15) ----------
__global__ __launch_bounds__(512) void k_final(
    const float* __restrict__ mp_partial,
    const float* __restrict__ acc_part, const float* __restrict__ acc_mass,
    const float* __restrict__ acc_pos,
    const float* __restrict__ g2, const float* __restrict__ beta2,
    const float* __restrict__ W_r1, const float* __restrict__ b_r1,
    const float* __restrict__ W_r2, const float* __restrict__ b_r2,
    const float* __restrict__ W_s1, const float* __restrict__ b_s1,
    const float* __restrict__ W_s2, const float* __restrict__ b_s2,
    float* __restrict__ out_pf, float* __restrict__ out_pos, float* __restrict__ out_sal,
    int use_part) {
  __shared__ float s_pf[8 * DP];
  __shared__ float s_h[8 * DP];
  __shared__ float s_t[8 * 512];
  __shared__ float s_pff[8 * DP];
  __shared__ float s_s1v[8 * 64];
  __shared__ float s_m[8];
  __shared__ float s_mpred[24];
  __shared__ float s_r2p[8 * DP];
  __shared__ float s_s1p[8][8][64];
  const int b = blockIdx.x;
  const int tid = threadIdx.x;
  const int lane = tid & 63, wave = tid >> 6;

  if (use_part) {
    if (tid < 384) {
      const int vk = tid >> 4;
      const int jt = tid & 15;
      const int v = vk >> 3, k = vk & 7;
      const float* q = mp_partial + ((size_t)b * 64 + jt * 4) * 32 + v * 8 + k;
      float part = q[0] + q[32] + q[64] + q[96];
      #pragma unroll
      for (int d = 1; d < 16; d <<= 1) part += __shfl_xor(part, d);
      if (jt == 0) s_mpred[vk] = part;
    }
    __syncthreads();
    if (tid < 8) s_m[tid] = fmaxf(s_mpred[tid], 1e-6f);
    __syncthreads();
    if (tid < 16) {
      const int k = tid >> 1, xy = tid & 1;
      out_pos[b * 16 + tid] = s_mpred[(xy + 1) * 8 + k] / s_m[k];
    }
  } else {
    if (tid < 8) s_m[tid] = fmaxf(acc_mass[b * 8 + tid], 1e-6f);
    if (tid >= 64 && tid < 80) {
      int t = tid - 64;
      out_pos[b * 16 + t] = acc_pos[b * 16 + t] / fmaxf(acc_mass[b * 8 + (t >> 1)], 1e-6f);
    }
    __syncthreads();
  }
  __syncthreads();

  #pragma unroll
  for (int i = 0; i < 4; i++) {
    const int idx = i * 512 + tid;
    s_pf[idx] = acc_part[(size_t)b * 2048 + idx] / s_m[idx >> 8];
  }
  __syncthreads();

  {
    const int r = wave;
    f32x4 x = *(const f32x4*)&s_pf[r * DP + lane * 4];
    float s = x[0] + x[1] + x[2] + x[3];
    float q = x[0] * x[0] + x[1] * x[1] + x[2] * x[2] + x[3] * x[3];
    #pragma unroll
    for (int d = 1; d < 64; d <<= 1) { s += __shfl_xor(s, d); q += __shfl_xor(q, d); }
    const float mean = s * (1.f / 256.f);
    const float var  = q * (1.f / 256.f) - mean * mean;
    const float rstd = rsqrtf(var + 1e-5f);
    #pragma unroll
    for (int j = 0; j < 4; j++) {
      const int col = lane * 4 + j;
      s_h[r * DP + col] = (x[j] - mean) * rstd * g2[col] + beta2[col];
    }
  }
  __syncthreads();

  {
    const int o = tid;
    float a[8];
    #pragma unroll
    for (int r = 0; r < 8; r++) a[r] = 0.f;
    #pragma unroll 8
    for (int c = 0; c < DP; c++) {
      const float w = W_r1[c * 512 + o];
      #pragma unroll
      for (int r = 0; r < 8; r++) a[r] += s_h[r * DP + c] * w;
    }
    const float bb = b_r1[o];
    #pragma unroll
    for (int r = 0; r < 8; r++) s_t[r * 512 + o] = gelu_f(a[r] + bb);
  }
  __syncthreads();

  {
    const int g = tid >> 8, o = tid & 255;
    float a[8];
    #pragma unroll
    for (int r = 0; r < 8; r++) a[r] = 0.f;
    #pragma unroll 8
    for (int cc = 0; cc < 256; cc++) {
      const int c = g * 256 + cc;
      const float w = W_r2[c * DP + o];
      #pragma unroll
      for (int r = 0; r < 8; r++) a[r] += s_t[r * 512 + c] * w;
    }
    if (g) {
      #pragma unroll
      for (int r = 0; r < 8; r++) s_r2p[r * DP + o] = a[r];
    }
    __syncthreads();
    if (!g) {
      const float bb = b_r2[o];
      #pragma unroll
      for (int r = 0; r < 8; r++) {
        float v = s_pf[r * DP + o] + a[r] + s_r2p[r * DP + o] + bb;
        s_pff[r * DP + o] = v;
        out_pf[(size_t)b * 2048 + r * DP + o] = v;
      }
    }
  }
  __syncthreads();

  {
    const int o = tid & 63, g = tid >> 6;
    float a[8];
    #pragma unroll
    for (int r = 0; r < 8; r++) a[r] = 0.f;
    #pragma unroll 8
    for (int cc = 0; cc < 32; cc++) {
      const int c = g * 32 + cc;
      const float w = W_s1[c * 64 + o];
      #pragma unroll
      for (int r = 0; r < 8; r++) a[r] += s_pff[r * DP + c] * w;
    }
    #pragma unroll
    for (int r = 0; r < 8; r++) s_s1p[g][r][o] = a[r];
  }
  __syncthreads();
  {
    const int r = tid >> 6, o = tid & 63;
    float a = 0.f;
    #pragma unroll
    for (int g = 0; g < 8; g++) a += s_s1p[g][r][o];
    s_s1v[r * 64 + o] = gelu_f(a + b_s1[o]);
  }
  __syncthreads();

  if (tid < 8) {
    float a = 0.f;
    for (int c = 0; c < 64; c++) a += s_s1v[tid * 64 + c] * W_s2[c];
    a += b_s2[0];
    out_sal[b * 8 + tid] = 1.f / (1.f + __expf(-a));
  }
}

extern "C" void kernel_launch(void* const* d_in, const int* in_sizes, int n_in,
                              void* d_out, int out_size, void* d_ws, size_t ws_size,
                              hipStream_t stream) {
  (void)in_sizes; (void)n_in; (void)out_size;
  const float* patch  = (const float*)d_in[0];
  const float* W_proj = (const float*)d_in[3];
  const float* b_proj = (const float*)d_in[4];
  const float* g1     = (const float*)d_in[5];
  const float* beta1  = (const float*)d_in[6];
  const float* proto  = (const float*)d_in[7];
  const float* g2     = (const float*)d_in[8];
  const float* beta2  = (const float*)d_in[9];
  const float* W_r1   = (const float*)d_in[10];
  const float* b_r1   = (const float*)d_in[11];
  const float* W_r2   = (const float*)d_in[12];
  const float* b_r2   = (const float*)d_in[13];
  const float* W_s1   = (const float*)d_in[14];
  const float* b_s1   = (const float*)d_in[15];
  const float* W_s2   = (const float*)d_in[16];
  const float* b_s2   = (const float*)d_in[17];

  float* out = (float*)d_out;
  float* out_pf     = out;                 // [64,8,256]
  float* out_pos    = out + 131072;        // [64,8,2]
  float* out_assign = out + 132096;        // [64,4096,8]
  float* out_sal    = out + 2229248;       // [64,8]
  float* out_feat   = out + 2229760;       // [64,4096,256]

  char* ws = (char*)d_ws;
  unsigned short* wT  = (unsigned short*)ws;               // 196608 B
  float* protoN       = (float*)(ws + 196608);             // 8192 B
  unsigned short* pbf = (unsigned short*)(ws + 204800);    // 8192 B
  float* acc_part     = (float*)(ws + 262144);             // 524288 B
  float* acc_mass     = (float*)(ws + 786432);             // 2048 B
  float* acc_pos      = (float*)(ws + 788480);             // 4096 B
  unsigned short* part_partial = (unsigned short*)(ws + 1048576); // 16777216 B (bf16)
  float* mp_partial   = (float*)(ws + 1048576 + 16777216); // 524288 B

  const size_t need_part = 1048576ull + 16777216ull + 524288ull;
  const int use_part = (ws_size >= need_part) ? 1 : 0;

  if (!use_part) hipMemsetAsync(ws + 262144, 0, 530432, stream);
  k_setup<<<385, 256, 0, stream>>>(W_proj, wT, proto, protoN, pbf);
  k_fused<<<4096, 256, 0, stream>>>(patch, b_proj, g1, beta1, wT, pbf,
                                    out_feat, out_assign,
                                    part_partial, mp_partial,
                                    acc_part, acc_mass, acc_pos, use_part);
  if (use_part) k_reduce<<<512, 256, 0, stream>>>(part_partial, acc_part);
  k_final<<<64, 512, 0, stream>>>(mp_partial, acc_part, acc_mass, acc_pos,
                                  g2, beta2, W_r1, b_r1, W_r2, b_r2,
                                  W_s1, b_s1, W_s2, b_s2,
                                  out_pf, out_pos, out_sal, use_part);
}